// Round 6
// baseline (80.927 us; speedup 1.0000x reference)
//
#include <hip/hip_runtime.h>

// Damped electrostatics with shifted-force cutoff.
// d is recomputed from vec (d == |v| by construction) -> no dist stream.
// Packed atom tables in d_ws (4.0 MB total, L2-resident):
//   A  [N] f32x4 : (q, dip.x, dip.y, dip.z)
//   B0 [N] f32x4 : (Q00-trQ/3, Q11-trQ/3, Q22-trQ/3, Q01+Q10)
//   B1 [N] f32x2 : (Q02+Q20, Q12+Q21)
// 2 edges per thread: all 8 gathers + 3 vec loads in flight together.
// Streams (vec/idx/out) are non-temporal so they don't evict the tables.

#define CUTOFF      10.0f
#define KEHALF      7.199822675975274f

typedef float f32x4 __attribute__((ext_vector_type(4)));
typedef float f32x2 __attribute__((ext_vector_type(2)));
typedef int   i32x2 __attribute__((ext_vector_type(2)));

__global__ __launch_bounds__(256) void pack_atoms_kernel(
    const float* __restrict__ q,
    const float* __restrict__ dip,
    const float* __restrict__ quad,
    f32x4* __restrict__ tabA,
    f32x4* __restrict__ tabB0,
    f32x2* __restrict__ tabB1,
    int N)
{
    int i = blockIdx.x * blockDim.x + threadIdx.x;
    if (i >= N) return;
    const float* dp = dip + 3 * (size_t)i;
    const float* qp = quad + 9 * (size_t)i;
    f32x4 a = {q[i], dp[0], dp[1], dp[2]};
    tabA[i] = a;

    float q00 = qp[0], q01 = qp[1], q02 = qp[2];
    float q10 = qp[3], q11 = qp[4], q12 = qp[5];
    float q20 = qp[6], q21 = qp[7], q22 = qp[8];
    float trQ3 = (q00 + q11 + q22) * (1.0f / 3.0f);
    f32x4 b0 = {q00 - trQ3, q11 - trQ3, q22 - trQ3, q01 + q10};
    f32x2 b1 = {q02 + q20, q12 + q21};
    tabB0[i] = b0;
    tabB1[i] = b1;
}

__device__ __forceinline__ float edge_energy(
    float vx, float vy, float vz,
    f32x4 au, f32x4 av, f32x4 b0, f32x2 b1)
{
    float d2 = vx * vx + vy * vy + vz * vz;
    float d = sqrtf(d2);
    float inv_d = 1.0f / d;
    float inv_d2 = inv_d * inv_d;

    // poly5 switch, cutoff_sr = 4
    float x = d * 0.25f;
    float x2 = x * x;
    float x3 = x2 * x;
    float sw = 1.0f - x3 * (10.0f - 15.0f * x + 6.0f * x2);
    sw = (x < 1.0f) ? sw : 0.0f;
    float chi = sw * rsqrtf(d2 + 1.0f) + (1.0f - sw) * inv_d;

    // shifted-force corrections (cutoff = 10)
    float c1 = chi - (0.2f   - 0.01f   * d);
    float chi2 = chi * chi;
    float chi3 = chi2 * chi;
    float c2 = chi2 - (0.03f  - 0.002f  * d);
    float c3 = chi3 - (0.004f - 0.0003f * d);

    float qu = au.x, qv = av.x;
    float Ee = qu * qv * c1;

    float dot_uv = (vx * av.y + vy * av.z + vz * av.w) * inv_d;
    float dot_vu = (vx * au.y + vy * au.z + vz * au.w) * inv_d;
    float dd     = au.y * av.y + au.z * av.z + au.w * av.w;

    Ee += 2.0f * qu * dot_uv * c2;
    Ee += (dd - 3.0f * dot_uv * dot_vu) * c3;

    // traceless quadrupole contraction (uses sum(v_i^2) == d^2)
    float num = b0.x * vx * vx + b0.y * vy * vy + b0.z * vz * vz
              + b0.w * vx * vy + b1.x * vx * vz + b1.y * vy * vz;
    Ee += qu * (num * inv_d2) * c3;

    Ee *= KEHALF;
    return (d <= CUTOFF) ? Ee : 0.0f;
}

__global__ __launch_bounds__(256) void damped_elec_2e(
    const f32x4* __restrict__ tabA,
    const f32x4* __restrict__ tabB0,
    const f32x2* __restrict__ tabB1,
    const float* __restrict__ vec,    // [E,3]
    const int*   __restrict__ idx_u,  // [E]
    const int*   __restrict__ idx_v,  // [E]
    float*       __restrict__ out,    // [E]
    int E)
{
    int t = blockIdx.x * blockDim.x + threadIdx.x;
    size_t base = 2 * (size_t)t;

    if (base + 1 < (size_t)E) {
        // streams (non-temporal)
        i32x2 uu = __builtin_nontemporal_load((const i32x2*)(idx_u + base));
        i32x2 vv = __builtin_nontemporal_load((const i32x2*)(idx_v + base));
        const f32x2* vp = (const f32x2*)(vec + 3 * base);
        f32x2 w0 = __builtin_nontemporal_load(vp + 0);   // vx0 vy0
        f32x2 w1 = __builtin_nontemporal_load(vp + 1);   // vz0 vx1
        f32x2 w2 = __builtin_nontemporal_load(vp + 2);   // vy1 vz1

        // all gathers issued together (L2-resident tables)
        f32x4 au0 = tabA[uu.x];
        f32x4 au1 = tabA[uu.y];
        f32x4 av0 = tabA[vv.x];
        f32x4 av1 = tabA[vv.y];
        f32x4 b00 = tabB0[vv.x];
        f32x4 b01 = tabB0[vv.y];
        f32x2 b10 = tabB1[vv.x];
        f32x2 b11 = tabB1[vv.y];

        float r0 = edge_energy(w0.x, w0.y, w1.x, au0, av0, b00, b10);
        float r1 = edge_energy(w1.y, w2.x, w2.y, au1, av1, b01, b11);

        f32x2 res = {r0, r1};
        __builtin_nontemporal_store(res, (f32x2*)(out + base));
    } else if (base < (size_t)E) {
        // single trailing edge
        int u = idx_u[base];
        int v = idx_v[base];
        float vx = vec[3 * base + 0];
        float vy = vec[3 * base + 1];
        float vz = vec[3 * base + 2];
        out[base] = edge_energy(vx, vy, vz, tabA[u], tabA[v], tabB0[v], tabB1[v]);
    }
}

// Fallback if ws_size is too small for the packed tables.
__global__ __launch_bounds__(256) void damped_elec_unpacked(
    const float* __restrict__ q,
    const float* __restrict__ dip,
    const float* __restrict__ quad,
    const float* __restrict__ vec,
    const int*   __restrict__ idx_u,
    const int*   __restrict__ idx_v,
    float*       __restrict__ out,
    int E)
{
    int i = blockIdx.x * blockDim.x + threadIdx.x;
    if (i >= E) return;
    float vx = vec[3 * (size_t)i + 0];
    float vy = vec[3 * (size_t)i + 1];
    float vz = vec[3 * (size_t)i + 2];
    int u = idx_u[i];
    int v = idx_v[i];
    const float* pu = dip + 3 * (size_t)u;
    const float* pv = dip + 3 * (size_t)v;
    const float* pq = quad + 9 * (size_t)v;

    f32x4 au = {q[u], pu[0], pu[1], pu[2]};
    f32x4 av = {q[v], pv[0], pv[1], pv[2]};
    float trQ3 = (pq[0] + pq[4] + pq[8]) * (1.0f / 3.0f);
    f32x4 b0 = {pq[0] - trQ3, pq[4] - trQ3, pq[8] - trQ3, pq[1] + pq[3]};
    f32x2 b1 = {pq[2] + pq[6], pq[5] + pq[7]};
    out[i] = edge_energy(vx, vy, vz, au, av, b0, b1);
}

extern "C" void kernel_launch(void* const* d_in, const int* in_sizes, int n_in,
                              void* d_out, int out_size, void* d_ws, size_t ws_size,
                              hipStream_t stream) {
    const float* q    = (const float*)d_in[0];  // atomic_charges      [N]
    const float* dip  = (const float*)d_in[1];  // atomic_dipoles      [N,3]
    const float* quad = (const float*)d_in[2];  // atomic_quadrupoles  [N,3,3]
    const float* vec  = (const float*)d_in[3];  // vectors_uv          [E,3]
    const int*   iu   = (const int*)d_in[5];    // idx_u               [E]
    const int*   iv   = (const int*)d_in[6];    // idx_v               [E]
    float* out = (float*)d_out;

    int N = in_sizes[0];
    int E = in_sizes[4];
    int block = 256;

    size_t needA  = (size_t)N * 16;
    size_t needB0 = (size_t)N * 16;
    size_t needB1 = (size_t)N * 8;
    if (ws_size >= needA + needB0 + needB1) {
        f32x4* tabA  = (f32x4*)d_ws;
        f32x4* tabB0 = (f32x4*)((char*)d_ws + needA);
        f32x2* tabB1 = (f32x2*)((char*)d_ws + needA + needB0);
        int pgrid = (N + block - 1) / block;
        pack_atoms_kernel<<<pgrid, block, 0, stream>>>(q, dip, quad, tabA, tabB0, tabB1, N);
        int nthreads = (E + 1) / 2;
        int egrid = (nthreads + block - 1) / block;
        damped_elec_2e<<<egrid, block, 0, stream>>>(tabA, tabB0, tabB1, vec, iu, iv, out, E);
    } else {
        int egrid = (E + block - 1) / block;
        damped_elec_unpacked<<<egrid, block, 0, stream>>>(q, dip, quad, vec, iu, iv, out, E);
    }
}

// Round 7
// 58.262 us; speedup vs baseline: 1.3890x; 1.3890x over previous
//
#include <hip/hip_runtime.h>

// Damped electrostatics with shifted-force cutoff.
// Single packed atom table in d_ws, 32 B/atom (3.2 MB, L2-resident):
//   w0 (f32x4): q, dip.x, dip.y, dip.z
//   w1 (u32x4): bf16{ t00, t11, t22, s01, s02, s12 }, pad
//     where t_ii = Q_ii - trQ/3 (traceless diag), s_ij = Q_ij + Q_ji.
// Per edge: u touches 1 cache line, v touches 1 cache line (both halves of
// one 32B record). d is recomputed from vec (d == |v| by construction).
// Streams (vec/idx/out) non-temporal so they don't evict the table from L2.

#define CUTOFF      10.0f
#define KEHALF      7.199822675975274f

typedef float    f32x4 __attribute__((ext_vector_type(4)));
typedef unsigned u32x4 __attribute__((ext_vector_type(4)));

__device__ __forceinline__ unsigned f2bf(float f) {
    unsigned u = __float_as_uint(f);
    return (u + 0x7FFFu + ((u >> 16) & 1u)) >> 16;   // round-to-nearest-even
}
__device__ __forceinline__ float bflo(unsigned p) { return __uint_as_float(p << 16); }
__device__ __forceinline__ float bfhi(unsigned p) { return __uint_as_float(p & 0xFFFF0000u); }

__global__ __launch_bounds__(256) void pack_atoms_kernel(
    const float* __restrict__ q,
    const float* __restrict__ dip,
    const float* __restrict__ quad,
    f32x4* __restrict__ table,        // [N,2] 16B words
    int N)
{
    int i = blockIdx.x * blockDim.x + threadIdx.x;
    if (i >= N) return;
    const float* dp = dip + 3 * (size_t)i;
    const float* qp = quad + 9 * (size_t)i;

    f32x4 w0 = {q[i], dp[0], dp[1], dp[2]};

    float q00 = qp[0], q01 = qp[1], q02 = qp[2];
    float q10 = qp[3], q11 = qp[4], q12 = qp[5];
    float q20 = qp[6], q21 = qp[7], q22 = qp[8];
    float trQ3 = (q00 + q11 + q22) * (1.0f / 3.0f);

    unsigned p0 = f2bf(q00 - trQ3) | (f2bf(q11 - trQ3) << 16);
    unsigned p1 = f2bf(q22 - trQ3) | (f2bf(q01 + q10) << 16);
    unsigned p2 = f2bf(q02 + q20) | (f2bf(q12 + q21) << 16);
    u32x4 w1 = {p0, p1, p2, 0u};

    table[2 * (size_t)i + 0] = w0;
    table[2 * (size_t)i + 1] = __builtin_bit_cast(f32x4, w1);
}

__device__ __forceinline__ float edge_energy(
    float vx, float vy, float vz,
    f32x4 au, f32x4 av, u32x4 bv)
{
    float d2 = vx * vx + vy * vy + vz * vz;
    float d = sqrtf(d2);
    float inv_d = 1.0f / d;
    float inv_d2 = inv_d * inv_d;

    // poly5 switch, cutoff_sr = 4
    float x = d * 0.25f;
    float x2 = x * x;
    float x3 = x2 * x;
    float sw = 1.0f - x3 * (10.0f - 15.0f * x + 6.0f * x2);
    sw = (x < 1.0f) ? sw : 0.0f;
    float chi = sw * rsqrtf(d2 + 1.0f) + (1.0f - sw) * inv_d;

    // shifted-force corrections (cutoff = 10)
    float c1 = chi - (0.2f   - 0.01f   * d);
    float chi2 = chi * chi;
    float chi3 = chi2 * chi;
    float c2 = chi2 - (0.03f  - 0.002f  * d);
    float c3 = chi3 - (0.004f - 0.0003f * d);

    float qu = au.x, qv = av.x;
    float Ee = qu * qv * c1;

    float dot_uv = (vx * av.y + vy * av.z + vz * av.w) * inv_d;
    float dot_vu = (vx * au.y + vy * au.z + vz * au.w) * inv_d;
    float dd     = au.y * av.y + au.z * av.z + au.w * av.w;

    Ee += 2.0f * qu * dot_uv * c2;
    Ee += (dd - 3.0f * dot_uv * dot_vu) * c3;

    // traceless quadrupole contraction (uses sum(v_i^2) == d^2)
    float t00 = bflo(bv.x), t11 = bfhi(bv.x);
    float t22 = bflo(bv.y), s01 = bfhi(bv.y);
    float s02 = bflo(bv.z), s12 = bfhi(bv.z);
    float num = t00 * vx * vx + t11 * vy * vy + t22 * vz * vz
              + s01 * vx * vy + s02 * vx * vz + s12 * vy * vz;
    Ee += qu * (num * inv_d2) * c3;

    Ee *= KEHALF;
    return (d <= CUTOFF) ? Ee : 0.0f;
}

__global__ __launch_bounds__(256) void damped_elec_packed32(
    const f32x4* __restrict__ table,  // [N,2]
    const float* __restrict__ vec,    // [E,3]
    const int*   __restrict__ idx_u,  // [E]
    const int*   __restrict__ idx_v,  // [E]
    float*       __restrict__ out,    // [E]
    int E)
{
    int i = blockIdx.x * blockDim.x + threadIdx.x;
    if (i >= E) return;

    // streams (non-temporal: keep L2 for the table)
    int u = __builtin_nontemporal_load(idx_u + i);
    int v = __builtin_nontemporal_load(idx_v + i);
    float vx = __builtin_nontemporal_load(vec + 3 * (size_t)i + 0);
    float vy = __builtin_nontemporal_load(vec + 3 * (size_t)i + 1);
    float vz = __builtin_nontemporal_load(vec + 3 * (size_t)i + 2);

    // gathers: 2 unique lines per edge (u: 1, v: 1)
    f32x4 au = table[2 * (size_t)u];
    f32x4 av = table[2 * (size_t)v + 0];
    u32x4 bv = __builtin_bit_cast(u32x4, table[2 * (size_t)v + 1]);

    float r = edge_energy(vx, vy, vz, au, av, bv);
    __builtin_nontemporal_store(r, out + i);
}

// Fallback if ws_size is too small for the packed table.
__global__ __launch_bounds__(256) void damped_elec_unpacked(
    const float* __restrict__ q,
    const float* __restrict__ dip,
    const float* __restrict__ quad,
    const float* __restrict__ vec,
    const int*   __restrict__ idx_u,
    const int*   __restrict__ idx_v,
    float*       __restrict__ out,
    int E)
{
    int i = blockIdx.x * blockDim.x + threadIdx.x;
    if (i >= E) return;
    float vx = vec[3 * (size_t)i + 0];
    float vy = vec[3 * (size_t)i + 1];
    float vz = vec[3 * (size_t)i + 2];
    int u = idx_u[i];
    int v = idx_v[i];
    const float* pu = dip + 3 * (size_t)u;
    const float* pv = dip + 3 * (size_t)v;
    const float* pq = quad + 9 * (size_t)v;

    f32x4 au = {q[u], pu[0], pu[1], pu[2]};
    f32x4 av = {q[v], pv[0], pv[1], pv[2]};
    float trQ3 = (pq[0] + pq[4] + pq[8]) * (1.0f / 3.0f);
    unsigned p0 = f2bf(pq[0] - trQ3) | (f2bf(pq[4] - trQ3) << 16);
    unsigned p1 = f2bf(pq[8] - trQ3) | (f2bf(pq[1] + pq[3]) << 16);
    unsigned p2 = f2bf(pq[2] + pq[6]) | (f2bf(pq[5] + pq[7]) << 16);
    u32x4 bv = {p0, p1, p2, 0u};
    out[i] = edge_energy(vx, vy, vz, au, av, bv);
}

extern "C" void kernel_launch(void* const* d_in, const int* in_sizes, int n_in,
                              void* d_out, int out_size, void* d_ws, size_t ws_size,
                              hipStream_t stream) {
    const float* q    = (const float*)d_in[0];  // atomic_charges      [N]
    const float* dip  = (const float*)d_in[1];  // atomic_dipoles      [N,3]
    const float* quad = (const float*)d_in[2];  // atomic_quadrupoles  [N,3,3]
    const float* vec  = (const float*)d_in[3];  // vectors_uv          [E,3]
    const int*   iu   = (const int*)d_in[5];    // idx_u               [E]
    const int*   iv   = (const int*)d_in[6];    // idx_v               [E]
    float* out = (float*)d_out;

    int N = in_sizes[0];
    int E = in_sizes[4];
    int block = 256;
    int egrid = (E + block - 1) / block;

    size_t need = (size_t)N * 32;
    if (ws_size >= need) {
        f32x4* table = (f32x4*)d_ws;
        int pgrid = (N + block - 1) / block;
        pack_atoms_kernel<<<pgrid, block, 0, stream>>>(q, dip, quad, table, N);
        damped_elec_packed32<<<egrid, block, 0, stream>>>(table, vec, iu, iv, out, E);
    } else {
        damped_elec_unpacked<<<egrid, block, 0, stream>>>(q, dip, quad, vec, iu, iv, out, E);
    }
}